// Round 8
// baseline (2794.595 us; speedup 1.0000x reference)
//
#include <hip/hip_runtime.h>

// Echo-state RNN, B=32, T=2048, NH=512, NI=NO=1.  W_hh ~90% exact zeros.
// One workgroup (CU) per batch; thread p owns row perm[p], rows sorted by nnz
// DESC so each wave's slot count ~= its own lane max (~55 avg, not the global
// ~88). Gather slots scheduled with a SOFT cap of 2 per (half-wave, bank):
// round-7 post-mortem showed the hard cap-1 constraint lower-bounds slots at
// the per-half bank degree (~68-76) and re-inflated the gather count to
// round-1 levels. Cap-2 keeps conflicts tiny (<=2 extra phases, rare) while
// letting slot count hit the lane-degree floor. Sparse rows in REGISTERS
// (static indexing; first PIN slots pinned via asm). Gathers are 1 ds_read
// each (byte offsets). Fast tanh via exp+rcp. z-reduction on the VALU pipe
// via DPP; in-loop barrier drains lgkmcnt only.

#define NH   512
#define TT   2048
#define BB   32
#define PAD  96
#define PIN  64          // slots pinned into VGPRs (2 regs/slot)

// ---------------------------------------------------------------------------
// A: nnz per row (wave-per-row ballot count)
// ---------------------------------------------------------------------------
__global__ __launch_bounds__(512) void count_nnz(
    const float* __restrict__ Whh, int* __restrict__ nnz) {
  const int wib  = threadIdx.x >> 6;
  const int lane = threadIdx.x & 63;
  const int row  = blockIdx.x * 8 + wib;
  const float* wrow = Whh + (size_t)row * NH;
  int cnt = 0;
  for (int c = 0; c < NH / 64; ++c)
    cnt += __popcll(__ballot(wrow[c * 64 + lane] != 0.0f));
  if (lane == 0) nnz[row] = cnt;
}

// ---------------------------------------------------------------------------
// B: rank rows by nnz descending (stable). perm[p] = row at sorted pos p.
// ---------------------------------------------------------------------------
__global__ __launch_bounds__(512) void sort_rows(
    const int* __restrict__ nnz, int* __restrict__ perm) {
  __shared__ int nl[NH];
  const int j = threadIdx.x;
  const int my = nnz[j];
  nl[j] = my;
  __syncthreads();
  int r = 0;
  const int4* p4 = (const int4*)nl;
  for (int i = 0; i < NH / 4; ++i) {
    int4 v = p4[i];
    const int base = i * 4;
    r += (v.x > my) || (v.x == my && base + 0 < j);
    r += (v.y > my) || (v.y == my && base + 1 < j);
    r += (v.z > my) || (v.z == my && base + 2 < j);
    r += (v.w > my) || (v.w == my && base + 3 < j);
  }
  perm[r] = j;
}

// ---------------------------------------------------------------------------
// C: gather schedule, one WAVE per block (grid=8), rows nnz-sorted so lane
// degrees within a wave are similar. Per slot: each unplaced lane proposes
// its next unconsumed bank in lane-rotated order; acceptance = atomicAdd
// count, accept if old < cap. Rounds 0..2 use cap 1 (prefer empty banks),
// later rounds cap 2 (soft cap; exclusions reset at the escalation). Force
// backstop near PAD guarantees completion.
// ---------------------------------------------------------------------------
__global__ __launch_bounds__(64) void build_schedule(
    const float* __restrict__ Whh, const int* __restrict__ perm,
    float* __restrict__ vals, unsigned* __restrict__ offs,
    int* __restrict__ cntw) {
  __shared__ int cnt[2][32];
  const int lane = threadIdx.x;
  const int wid  = blockIdx.x;
  const int p    = wid * 64 + lane;
  const int half = lane >> 5;
  const int home = lane & 31;
  const int row  = perm[p];
  const float* wrow = Whh + (size_t)row * NH;

  // reg r: lo16 = presence mask of bank 2r (bit m <=> col 2r+32m nz), hi16 = 2r+1
  unsigned occ32[16];
  int remaining = 0;
  unsigned nonempty = 0;
  #pragma unroll
  for (int r = 0; r < 16; ++r) {
    unsigned lo = 0, hi = 0;
    #pragma unroll
    for (int m = 0; m < 16; ++m) {
      lo |= (wrow[(2 * r)     + 32 * m] != 0.f) ? (1u << m) : 0u;
      hi |= (wrow[(2 * r + 1) + 32 * m] != 0.f) ? (1u << m) : 0u;
    }
    occ32[r] = lo | (hi << 16);
    remaining += __popc(lo) + __popc(hi);
    if (lo) nonempty |= 1u << (2 * r);
    if (hi) nonempty |= 1u << (2 * r + 1);
  }

  int s = 0;
  while (__ballot(remaining > 0) != 0ull && s < PAD) {
    cnt[half][home] = 0;                      // covers both halves x 32 banks
    __builtin_amdgcn_wave_barrier();

    bool placed = false;
    int  mybank = 0;
    unsigned excl = 0;

    for (int round = 0; round < 10; ++round) {
      const int cap = (round < 3) ? 1 : 2;
      if (round == 3) excl = 0;               // cap escalated: retry everything
      unsigned cand = (placed || remaining == 0) ? 0u : (nonempty & ~excl);
      bool want = cand != 0u;
      int bl = 0;
      if (want) {                             // rotated-first-set proposal
        unsigned rot = home ? ((cand >> home) | (cand << (32 - home))) : cand;
        bl = (home + __ffs(rot) - 1) & 31;
      }
      if (__ballot(want) == 0ull) break;
      if (want) {
        int old = atomicAdd(&cnt[half][bl], 1);
        if (old < cap) { placed = true; mybank = bl; }
        else { atomicSub(&cnt[half][bl], 1); excl |= 1u << bl; }
      }
      __builtin_amdgcn_wave_barrier();
    }

    // backstop: must place now or we run out of slots (rare; may conflict)
    if (!placed && remaining > 0 && (PAD - s) <= remaining) {
      placed = true;
      mybank = __ffs(nonempty) - 1;
    }

    float v = 0.f; unsigned col = 0u;
    if (placed) {                             // consume lowest col of mybank
      #pragma unroll
      for (int r = 0; r < 16; ++r) {
        if (r == (mybank >> 1)) {
          unsigned w   = occ32[r];
          unsigned m16 = (mybank & 1) ? (w >> 16) : (w & 0xFFFFu);
          int m = __ffs(m16) - 1;
          col = (unsigned)(mybank + 32 * m);
          unsigned nm = m16 & (m16 - 1u);
          occ32[r] = (mybank & 1) ? ((w & 0x0000FFFFu) | (nm << 16))
                                  : ((w & 0xFFFF0000u) | nm);
          if (nm == 0u) nonempty &= ~(1u << mybank);
        }
      }
      v = wrow[col];
      --remaining;
    }
    vals[s * NH + p] = v;                     // idle lanes: harmless 0 * t[0]
    offs[s * NH + p] = col;
    ++s;
  }
  if (lane == 0) cntw[wid] = s;
  for (int e = s; e < PAD; ++e) {             // zero-fill tail slots
    vals[e * NH + p] = 0.f;
    offs[e * NH + p] = 0u;
  }
}

// ---------------------------------------------------------------------------
// DPP wave-64 sum reduction on the VALU pipe; lane 63 ends with the full sum.
// ---------------------------------------------------------------------------
template <int CTRL, int RM>
__device__ __forceinline__ float dppadd(float v) {
  int t = __builtin_amdgcn_update_dpp(0, __float_as_int(v), CTRL, RM, 0xF, true);
  return v + __int_as_float(t);
}
__device__ __forceinline__ float wave_sum_lane63(float v) {
  v = dppadd<0xB1,  0xF>(v);   // quad_perm [1,0,3,2]
  v = dppadd<0x4E,  0xF>(v);   // quad_perm [2,3,0,1]
  v = dppadd<0x141, 0xF>(v);   // row_half_mirror
  v = dppadd<0x140, 0xF>(v);   // row_mirror
  v = dppadd<0x142, 0xA>(v);   // row_bcast15 -> rows 1,3
  v = dppadd<0x143, 0xC>(v);   // row_bcast31 -> rows 2,3
  return v;                    // lane 63 = sum of 64
}

// fast tanh: (t-1)/(t+1), t = exp(2x), clamp |x|<=9.
__device__ __forceinline__ float ftanh(float x) {
  float xc = fminf(9.0f, fmaxf(-9.0f, x));
  float t  = __expf(2.0f * xc);
  return (t - 1.0f) * __builtin_amdgcn_rcpf(t + 1.0f);
}

// ---------------------------------------------------------------------------
// Main: one block per batch, 512 threads, 2048 sequential steps (x2 unroll).
// ---------------------------------------------------------------------------
#define GA(T_RD, E) (*(const float*)((const char*)(T_RD) + cidx[E]))

#define ESN_STEP(T_RD, T_WR, RWR, SIDX)                                      \
  {                                                                          \
    float d0 = 0.f, d1 = 0.f, d2 = 0.f, d3 = 0.f;                            \
    _Pragma("unroll")                                                        \
    for (int e = 0; e < PAD; e += 4) {                                       \
      if (e < cw) {                                                          \
        d0 = fmaf(wval[e + 0], GA(T_RD, e + 0), d0);                         \
        d1 = fmaf(wval[e + 1], GA(T_RD, e + 1), d1);                         \
        d2 = fmaf(wval[e + 2], GA(T_RD, e + 2), d2);                         \
        d3 = fmaf(wval[e + 3], GA(T_RD, e + 3), d3);                         \
      }                                                                      \
    }                                                                        \
    float dot  = (d0 + d1) + (d2 + d3);                                      \
    float xp   = x_lds[SIDX] * w_ih;                                         \
    float dhdt = ((dot - h) + xp) + z_prev * w_zh;                           \
    float hn   = h + 0.1f * dhdt;                                            \
    float thn  = ftanh(hn);                                                  \
    T_WR[row] = thn;                                                         \
    oh[(SIDX) * NH + row] = hn;                                              \
    float pzs = wave_sum_lane63(thn * w_hz);                                 \
    if (lane == 63) red[RWR][wid] = pzs;                                     \
    asm volatile("s_waitcnt lgkmcnt(0)\n\ts_barrier" ::: "memory");          \
    float4 r0 = *(const float4*)&red[RWR][0];                                \
    float4 r1 = *(const float4*)&red[RWR][4];                                \
    float z = ((r0.x + r0.y) + (r0.z + r0.w)) + ((r1.x + r1.y) + (r1.z + r1.w)); \
    if (p == 0) oz[SIDX] = z;                                                \
    z_prev = z; h = hn;                                                      \
  }

__global__ __launch_bounds__(512, 2) void esn_steps(
    const float* __restrict__ x,   const float* __restrict__ h0,
    const float* __restrict__ Wih, const float* __restrict__ Whz,
    const float* __restrict__ Wzh, const float* __restrict__ vals,
    const unsigned* __restrict__ offs, const int* __restrict__ perm,
    const int* __restrict__ cntw, float* __restrict__ out) {
  __shared__ float t_lds[2][NH];              // tanh(h), double-buffered
  __shared__ float x_lds[TT];                 // this batch's input row
  __shared__ __align__(16) float red[2][8];   // cross-wave partials for z

  const int p    = threadIdx.x;               // sorted position owned
  const int b    = blockIdx.x;
  const int lane = p & 63;
  const int wid  = p >> 6;
  const int row  = perm[p];                   // actual hidden unit

  float* t0 = t_lds[0];
  float* t1 = t_lds[1];

  for (int i = p; i < TT; i += NH) x_lds[i] = x[(size_t)b * TT + i];

  // wave-uniform slot count, rounded to the 4-wide chunking (tail slots are
  // zero-filled by the scheduler, so over-read is harmless).
  int cw = __builtin_amdgcn_readfirstlane((cntw[wid] + 3) & ~3);

  // scheduled entries -> registers (entry-major, coalesced). cidx holds BYTE
  // offsets so each gather is one ds_read.
  float    wval[PAD];
  unsigned cidx[PAD];
  #pragma unroll
  for (int e = 0; e < PAD; ++e) {
    wval[e] = vals[e * NH + p];
    cidx[e] = offs[e * NH + p] * 4u;
  }
  // pin the first PIN slots into VGPRs (asm outputs can't be rematerialized
  // from memory -> forced residency).
  #pragma unroll
  for (int e = 0; e < PIN; ++e)
    asm volatile("" : "+v"(wval[e]), "+v"(cidx[e]));

  const float w_ih = Wih[row];
  const float w_hz = Whz[row];
  const float w_zh = Wzh[row];
  float h = h0[(size_t)b * NH + row];

  float* oz = out + (size_t)b * TT;                        // z region [B,T,1]
  float* oh = out + (size_t)BB * TT + (size_t)b * TT * NH; // h region [B,T,NH]

  // ---- init: t0 = tanh(h0); z_prev = sum(tanh(h0) * Whz) ----
  float th0 = ftanh(h);
  t0[row] = th0;
  float pz = wave_sum_lane63(th0 * w_hz);
  if (lane == 63) red[0][wid] = pz;
  __syncthreads();
  float4 i0 = *(const float4*)&red[0][0];
  float4 i1 = *(const float4*)&red[0][4];
  float z_prev = ((i0.x + i0.y) + (i0.z + i0.w)) + ((i1.x + i1.y) + (i1.z + i1.w));

  // ---- 2048 sequential steps, x2 unrolled (constant buffer ptr per body) ----
  for (int s = 0; s < TT; s += 2) {
    ESN_STEP(t0, t1, 1, s);
    ESN_STEP(t1, t0, 0, s + 1);
  }
}

// ---------------------------------------------------------------------------
extern "C" void kernel_launch(void* const* d_in, const int* in_sizes, int n_in,
                              void* d_out, int out_size, void* d_ws,
                              size_t ws_size, hipStream_t stream) {
  const float* x   = (const float*)d_in[0];
  const float* h0  = (const float*)d_in[1];
  const float* Wih = (const float*)d_in[2];
  const float* Whh = (const float*)d_in[3];
  const float* Whz = (const float*)d_in[4];
  const float* Wzh = (const float*)d_in[5];
  float* out = (float*)d_out;

  float*    vals = (float*)d_ws;                     // PAD*NH f32 = 192 KB
  unsigned* offs = (unsigned*)(vals + PAD * NH);     // PAD*NH u32 = 192 KB
  int*      nnz  = (int*)(offs + PAD * NH);          // NH
  int*      perm = nnz + NH;                         // NH
  int*      cntw = perm + NH;                        // 8

  hipLaunchKernelGGL(count_nnz, dim3(NH / 8), dim3(512), 0, stream, Whh, nnz);
  hipLaunchKernelGGL(sort_rows, dim3(1), dim3(512), 0, stream, nnz, perm);
  hipLaunchKernelGGL(build_schedule, dim3(8), dim3(64), 0, stream,
                     Whh, perm, vals, offs, cntw);
  hipLaunchKernelGGL(esn_steps, dim3(BB), dim3(512), 0, stream,
                     x, h0, Wih, Whz, Wzh, vals, offs, perm, cntw, out);
}